// Round 2
// baseline (2283.806 us; speedup 1.0000x reference)
//
#include <hip/hip_runtime.h>

#define BBATCH 4
#define CCH 72
#define HROW 256
#define WCOL 256
#define HWSZ (HROW*WCOL)
#define NPC (BBATCH*HROW*WCOL)
#define BNEPS 1e-3f

__device__ __forceinline__ float clip8(float v){ return fminf(fmaxf(v,-8.f),8.f); }

// BN-train: consumer recomputes per-channel scale/shift from producer's sum/sumsq.
__device__ __forceinline__ void get_ss(int c, const float* __restrict__ sum, const float* __restrict__ ssq,
                                       const float* __restrict__ gam, const float* __restrict__ bet,
                                       float& sc, float& sh){
  float mean = sum[c] * (1.0f/(float)NPC);
  float var  = ssq[c] * (1.0f/(float)NPC) - mean*mean;
  sc = gam[c] * rsqrtf(var + BNEPS);
  sh = bet[c] - mean*sc;
}

// ---------------- Pointwise conv (CIN -> 72), fused input BN+clip, output raw + stats ----------
// block = 256 threads = one (b,h) row of 256 px; thread = 9 out-ch x 8 contiguous w.
// c-dimension processed in chunks of 36 to keep LDS at ~65KB (2 blocks/CU).
template<int CIN, int RAW>
__global__ __launch_bounds__(256) void k_pw(const float* __restrict__ in,
    float* __restrict__ out, const float* __restrict__ wgt,
    const float* __restrict__ psum, const float* __restrict__ pssq,
    const float* __restrict__ pgam, const float* __restrict__ pbet,
    float* __restrict__ osum, float* __restrict__ ossq)
{
  __shared__ float xs[36*WCOL];         // one 36-channel chunk of the row, fp32
  __shared__ float wlds[8*CIN*12];      // weights [og][c][12], k<9 valid, 16B-aligned groups
  __shared__ float tsc[CIN], tsh[CIN];
  const int tid = threadIdx.x;
  const int b = blockIdx.x >> 8;
  const int h = blockIdx.x & 255;

  if (RAW==0 && tid < CIN) get_ss(tid, psum,pssq,pgam,pbet, tsc[tid], tsh[tid]);

  for (int i = tid; i < 8*CIN*12; i += 256){
    int og = i / (CIN*12);
    int rem = i - og*(CIN*12);
    int c = rem / 12;
    int k = rem - c*12;
    wlds[i] = (k < 9) ? wgt[(og*9+k)*CIN + c] : 0.0f;
  }
  __syncthreads();

  const int wq = tid & 31;   // 8 contiguous w starting at wq*8
  const int og = tid >> 5;   // 9 output channels og*9..og*9+8
  float acc[9][8];
  #pragma unroll
  for (int k=0;k<9;++k){
    #pragma unroll
    for (int j=0;j<8;++j) acc[k][j]=0.f;
  }

  const size_t base_in = (size_t)b*CIN*HWSZ + (size_t)h*WCOL;
  for (int cb = 0; cb < CIN; cb += 36){
    if (cb) __syncthreads();          // xs reuse boundary
    for (int i = tid; i < 36*32; i += 256){
      int c = i >> 5, m = i & 31;
      const float4* p = (const float4*)(in + base_in + (size_t)(cb+c)*HWSZ + m*8);
      float4 v0 = p[0], v1 = p[1];
      if (RAW==0){
        float sc = tsc[cb+c], sh = tsh[cb+c];
        v0.x = clip8(v0.x*sc+sh); v0.y = clip8(v0.y*sc+sh);
        v0.z = clip8(v0.z*sc+sh); v0.w = clip8(v0.w*sc+sh);
        v1.x = clip8(v1.x*sc+sh); v1.y = clip8(v1.y*sc+sh);
        v1.z = clip8(v1.z*sc+sh); v1.w = clip8(v1.w*sc+sh);
      }
      float4* dst = (float4*)&xs[c*WCOL + m*8];
      dst[0] = v0; dst[1] = v1;
    }
    __syncthreads();

    #pragma unroll 4
    for (int c = 0; c < 36; ++c){
      const float4* xp = (const float4*)&xs[c*WCOL + wq*8];
      float4 x0 = xp[0], x1 = xp[1];
      float xv[8] = {x0.x,x0.y,x0.z,x0.w, x1.x,x1.y,x1.z,x1.w};
      const float* wp = &wlds[(og*CIN + cb + c)*12];
      float4 wa = *(const float4*)wp;
      float4 wb = *(const float4*)(wp+4);
      float w8 = wp[8];
      float wv[9] = {wa.x,wa.y,wa.z,wa.w, wb.x,wb.y,wb.z,wb.w, w8};
      #pragma unroll
      for (int k=0;k<9;++k){
        #pragma unroll
        for (int j=0;j<8;++j) acc[k][j] = fmaf(wv[k], xv[j], acc[k][j]);
      }
    }
  }

  const size_t base_out = (size_t)b*CCH*HWSZ + (size_t)h*WCOL + (size_t)wq*8;
  #pragma unroll
  for (int k=0;k<9;++k){
    int o = og*9 + k;
    float s=0.f, qq=0.f;
    #pragma unroll
    for (int j=0;j<8;++j){
      s += acc[k][j];
      qq = fmaf(acc[k][j], acc[k][j], qq);
    }
    float4 o0 = make_float4(acc[k][0],acc[k][1],acc[k][2],acc[k][3]);
    float4 o1 = make_float4(acc[k][4],acc[k][5],acc[k][6],acc[k][7]);
    float4* dst = (float4*)(out + base_out + (size_t)o*HWSZ);
    dst[0] = o0; dst[1] = o1;
    #pragma unroll
    for (int off=16; off; off>>=1){
      s  += __shfl_xor(s, off);
      qq += __shfl_xor(qq, off);
    }
    if (wq == 0){
      atomicAdd(&osum[o], s);
      atomicAdd(&ossq[o], qq);
    }
  }
}

// ---------------- IIR scan along H, fused input BN+ReLU (+optional residual), output raw + stats
// MODE 0: plain; MODE 1: also store transformed input (h0 -> hbuf); MODE 2: add hbuf(h0), store h1 -> hbuf.
template<int MODE>
__global__ __launch_bounds__(256) void k_iir(const float* __restrict__ in, float* __restrict__ out,
    const float* __restrict__ wabc, float* __restrict__ hbuf,
    const float* __restrict__ psum, const float* __restrict__ pssq,
    const float* __restrict__ pgam, const float* __restrict__ pbet,
    float* __restrict__ osum, float* __restrict__ ossq)
{
  const int tid = threadIdx.x;
  const int bc = blockIdx.x;          // b*CCH + c
  const int c = bc % CCH;
  float sc, sh; get_ss(c, psum,pssq,pgam,pbet, sc, sh);
  const float ka = wabc[c], kb = wabc[CCH+c], kcc = wabc[2*CCH+c];
  const size_t base = (size_t)bc*HWSZ + tid;
  float xprev=0.f, yprev=0.f, lsum=0.f, lssq=0.f;

  for (int hb = 0; hb < HROW; hb += 16){
    float x[16];
    #pragma unroll
    for (int j=0;j<16;++j){
      size_t idx = base + (size_t)(hb+j)*WCOL;
      float v = fmaxf(in[idx]*sc + sh, 0.f);
      if (MODE==1) hbuf[idx] = v;
      if (MODE==2){ v += hbuf[idx]; hbuf[idx] = v; }
      x[j] = v;
    }
    if (hb == 0){ xprev = x[0]; yprev = x[0]; }  // y0 = (a+b+c)*x0
    float t[16];
    t[0] = fmaf(ka, x[0], kb*xprev);
    #pragma unroll
    for (int j=1;j<16;++j) t[j] = fmaf(ka, x[j], kb*x[j-1]);
    #pragma unroll
    for (int j=0;j<16;++j){
      yprev = fmaf(kcc, yprev, t[j]);       // 1-FMA dependent chain
      out[base + (size_t)(hb+j)*WCOL] = yprev;
      lsum += yprev; lssq = fmaf(yprev,yprev,lssq);
    }
    xprev = x[15];
  }

  #pragma unroll
  for (int off=32; off; off>>=1){ lsum += __shfl_xor(lsum,off); lssq += __shfl_xor(lssq,off); }
  __shared__ float rs[4], rq[4];
  if ((tid&63)==0){ rs[tid>>6]=lsum; rq[tid>>6]=lssq; }
  __syncthreads();
  if (tid==0){
    atomicAdd(&osum[c], rs[0]+rs[1]+rs[2]+rs[3]);
    atomicAdd(&ossq[c], rq[0]+rq[1]+rq[2]+rq[3]);
  }
}

// ---------------- Depthwise 5-tap along W, fused input BN+clip, output raw + stats ----------
// block = 8 rows x 256 w of one (b,c); thread = 8 contiguous w of one row.
__global__ __launch_bounds__(256) void k_dw(const float* __restrict__ in, float* __restrict__ out,
    const float* __restrict__ wgt,
    const float* __restrict__ psum, const float* __restrict__ pssq,
    const float* __restrict__ pgam, const float* __restrict__ pbet,
    float* __restrict__ osum, float* __restrict__ ossq)
{
  __shared__ float xs[8*264];   // row stride 264, data at col 4+w, zero halo
  __shared__ float rs[4], rq[4];
  const int tid = threadIdx.x;
  const int ht = blockIdx.x & 31;
  const int bc = blockIdx.x >> 5;
  const int c = bc % CCH;
  float sc, sh; get_ss(c, psum,pssq,pgam,pbet, sc, sh);
  const float w0=wgt[c*5+0], w1=wgt[c*5+1], w2=wgt[c*5+2], w3=wgt[c*5+3], w4=wgt[c*5+4];
  const size_t base = (size_t)bc*HWSZ + (size_t)ht*(8*WCOL);

  if (tid < 64){
    int r = tid>>3, k = tid&7;
    xs[r*264 + (k<4 ? k : 256+k)] = 0.f;
  }
  const int r = tid >> 5, m = tid & 31;
  {
    const float4* p = (const float4*)(in + base + (size_t)r*WCOL + m*8);
    float4 v0 = p[0], v1 = p[1];
    v0.x = clip8(v0.x*sc+sh); v0.y = clip8(v0.y*sc+sh);
    v0.z = clip8(v0.z*sc+sh); v0.w = clip8(v0.w*sc+sh);
    v1.x = clip8(v1.x*sc+sh); v1.y = clip8(v1.y*sc+sh);
    v1.z = clip8(v1.z*sc+sh); v1.w = clip8(v1.w*sc+sh);
    float4* dst = (float4*)&xs[r*264 + 4 + m*8];
    dst[0] = v0; dst[1] = v1;
  }
  __syncthreads();
  float lsum=0.f, lssq=0.f;
  {
    const float* row = &xs[r*264 + m*8];
    float4 a0 = *(const float4*)(row+0);
    float4 a1 = *(const float4*)(row+4);
    float4 a2 = *(const float4*)(row+8);
    float4 a3 = *(const float4*)(row+12);
    float v[16] = {a0.x,a0.y,a0.z,a0.w, a1.x,a1.y,a1.z,a1.w,
                   a2.x,a2.y,a2.z,a2.w, a3.x,a3.y,a3.z,a3.w};
    float o[8];
    #pragma unroll
    for (int j=0;j<8;++j){
      float y = w0*v[j+2];
      y = fmaf(w1, v[j+3], y);
      y = fmaf(w2, v[j+4], y);
      y = fmaf(w3, v[j+5], y);
      y = fmaf(w4, v[j+6], y);
      o[j] = y;
      lsum += y; lssq = fmaf(y,y,lssq);
    }
    float4* dst = (float4*)(out + base + (size_t)r*WCOL + m*8);
    dst[0] = make_float4(o[0],o[1],o[2],o[3]);
    dst[1] = make_float4(o[4],o[5],o[6],o[7]);
  }
  #pragma unroll
  for (int off=32; off; off>>=1){ lsum += __shfl_xor(lsum,off); lssq += __shfl_xor(lssq,off); }
  if ((tid&63)==0){ rs[tid>>6]=lsum; rq[tid>>6]=lssq; }
  __syncthreads();
  if (tid==0){
    atomicAdd(&osum[c], rs[0]+rs[1]+rs[2]+rs[3]);
    atomicAdd(&ossq[c], rq[0]+rq[1]+rq[2]+rq[3]);
  }
}

// ---------------- Final: out = h1 + relu(BN(y12)) (fp32 output) ----------------
__global__ __launch_bounds__(256) void k_final(const float* __restrict__ y12, const float* __restrict__ h1,
    float* __restrict__ outp,
    const float* __restrict__ psum, const float* __restrict__ pssq,
    const float* __restrict__ pgam, const float* __restrict__ pbet)
{
  __shared__ float tsc[CCH], tsh[CCH];
  if (threadIdx.x < CCH) get_ss(threadIdx.x, psum,pssq,pgam,pbet, tsc[threadIdx.x], tsh[threadIdx.x]);
  __syncthreads();
  const size_t TOTALQ = (size_t)BBATCH*CCH*HWSZ/4;
  for (size_t q = (size_t)blockIdx.x*blockDim.x + threadIdx.x; q < TOTALQ;
       q += (size_t)gridDim.x*blockDim.x){
    int cch = (int)((q >> 14) % CCH);
    float sc = tsc[cch], sh = tsh[cch];
    float4 a = *(const float4*)(y12 + q*4);
    float4 b = *(const float4*)(h1 + q*4);
    float4 o;
    o.x = fmaxf(a.x*sc+sh, 0.f) + b.x;
    o.y = fmaxf(a.y*sc+sh, 0.f) + b.y;
    o.z = fmaxf(a.z*sc+sh, 0.f) + b.z;
    o.w = fmaxf(a.w*sc+sh, 0.f) + b.w;
    *(float4*)(outp + q*4) = o;
  }
}

extern "C" void kernel_launch(void* const* d_in, const int* in_sizes, int n_in,
                              void* d_out, int out_size, void* d_ws, size_t ws_size,
                              hipStream_t stream)
{
  (void)in_sizes; (void)n_in; (void)out_size;
  const float* x   = (const float*)d_in[0];
  const float* ew  = (const float*)d_in[1];
  const float* eg  = (const float*)d_in[3];
  const float* ebt = (const float*)d_in[4];
  const float* iw  = (const float*)d_in[5];
  const float* ig  = (const float*)d_in[6];
  const float* ibt = (const float*)d_in[7];
  const float* dwt = (const float*)d_in[8];
  const float* dg  = (const float*)d_in[10];
  const float* dbt = (const float*)d_in[11];
  const float* pw  = (const float*)d_in[12];
  const float* pg  = (const float*)d_in[14];
  const float* pbt = (const float*)d_in[15];
  float* outp = (float*)d_out;

  const size_t BUFE = (size_t)BBATCH*CCH*HWSZ;     // 18,874,368 elements
  const size_t BUFB = BUFE*sizeof(float);          // 75.5 MB
  const size_t STATSB = 13*144*sizeof(float);
  char* ws = (char*)d_ws;
  float* A = (float*)ws;
  float* H = (float*)(ws + BUFB);                  // shared h0/h1 buffer
  float* B;
  float* stats;
  if (ws_size >= 3*BUFB + STATSB + 256){
    B = (float*)(ws + 2*BUFB);
    stats = (float*)(ws + 3*BUFB);
  } else {
    // B ping-pong buffer lives in d_out (dead before k_final, which reads A and H only)
    B = (float*)d_out;
    stats = (float*)(ws + 2*BUFB);
  }
  #define SS(s) (stats + (s)*144)
  #define SQ(s) (stats + (s)*144 + 72)

  hipMemsetAsync(stats, 0, STATSB, stream);

  dim3 blk(256);
  // s0: expand pointwise (fp32 x -> y0 in A), raw stats0
  k_pw<36,1><<<BBATCH*HROW, blk, 0, stream>>>(x, A, ew,
      nullptr,nullptr,nullptr,nullptr, SS(0),SQ(0));
  // unit 0
  k_iir<1><<<BBATCH*CCH, blk, 0, stream>>>(A, B, iw+0,   H, SS(0),SQ(0), eg, ebt, SS(1),SQ(1));
  k_dw    <<<BBATCH*CCH*32, blk, 0, stream>>>(B, A, dwt+0,    SS(1),SQ(1), ig+0,   ibt+0,   SS(2),SQ(2));
  k_pw<72,0><<<BBATCH*HROW, blk, 0, stream>>>(A, B, pw+0,     SS(2),SQ(2), dg+0,   dbt+0,   SS(3),SQ(3));
  // unit 1
  k_iir<0><<<BBATCH*CCH, blk, 0, stream>>>(B, A, iw+216, nullptr, SS(3),SQ(3), pg+0,  pbt+0,  SS(4),SQ(4));
  k_dw    <<<BBATCH*CCH*32, blk, 0, stream>>>(A, B, dwt+360,  SS(4),SQ(4), ig+72,  ibt+72,  SS(5),SQ(5));
  k_pw<72,0><<<BBATCH*HROW, blk, 0, stream>>>(B, A, pw+5184,  SS(5),SQ(5), dg+72,  dbt+72,  SS(6),SQ(6));
  // unit 2 (residual: h1 = h0 + relu(BN(y6)); IIR on h1; h1 kept in H)
  k_iir<2><<<BBATCH*CCH, blk, 0, stream>>>(A, B, iw+432, H, SS(6),SQ(6), pg+72, pbt+72, SS(7),SQ(7));
  k_dw    <<<BBATCH*CCH*32, blk, 0, stream>>>(B, A, dwt+720,  SS(7),SQ(7), ig+144, ibt+144, SS(8),SQ(8));
  k_pw<72,0><<<BBATCH*HROW, blk, 0, stream>>>(A, B, pw+10368, SS(8),SQ(8), dg+144, dbt+144, SS(9),SQ(9));
  // unit 3
  k_iir<0><<<BBATCH*CCH, blk, 0, stream>>>(B, A, iw+648, nullptr, SS(9),SQ(9), pg+144, pbt+144, SS(10),SQ(10));
  k_dw    <<<BBATCH*CCH*32, blk, 0, stream>>>(A, B, dwt+1080, SS(10),SQ(10), ig+216, ibt+216, SS(11),SQ(11));
  k_pw<72,0><<<BBATCH*HROW, blk, 0, stream>>>(B, A, pw+15552, SS(11),SQ(11), dg+216, dbt+216, SS(12),SQ(12));
  // out = h1 + relu(BN(y12))
  k_final<<<2048, blk, 0, stream>>>(A, H, outp, SS(12),SQ(12), pg+216, pbt+216);
  #undef SS
  #undef SQ
}